// Round 18
// baseline (807.961 us; speedup 1.0000x reference)
//
#include <hip/hip_runtime.h>
#include <math.h>

// Fused semantic attention — r16 staging/occupancy + r4's swapped-QK fragment
// algebra. Round-18 removes the two measured wastes left in r16:
//  (1) 4x-redundant exp (268M -> 67M): each wave owns one (qt, k-slice) S^T
//      tile via S^T = mfma(Kb, Q); every S element lives on exactly one lane.
//  (2) the Sst round-trip (4 ds_write + 2 ds_read + 1 barrier per chunk):
//      S^T D-frag == PV mfma_16x16x16f16 A-frag (r4-verified), so P goes
//      register->MFMA; out_s goes register->global as 16B/lane pieces
//      (r4-verified clean: 631 MB, no amplification).
// Per-wave O partials (one k-slice each) reduced once at the end via LDS
// atomics into Obuf (aliases Kb post-loop). LDS 17.5 KB; natural VGPR<=64
// -> 4 blocks/CU. 2 barriers/chunk. Epilogue (L2-replay out_a) unchanged.

#define BH 64
#define N 1024
#define D 64
#define TK 64
#define NC (N / TK)   // 16
#define KSTR 68       // f16 row stride: verified ~65K conflicts
#define LOG2E 1.44269504088896f
#define ESHIFT (-17.3123404907f)   // -12 * log2(e)

typedef float    f32x4 __attribute__((ext_vector_type(4)));
typedef _Float16 half8 __attribute__((ext_vector_type(8)));
typedef _Float16 half4 __attribute__((ext_vector_type(4)));
typedef __fp16   fp16x2 __attribute__((ext_vector_type(2)));  // cvt_pkrtz result

__global__ __launch_bounds__(512, 4) void attn_fused_kernel(
    const float* __restrict__ q, const float* __restrict__ k,
    const float* __restrict__ v, const float* __restrict__ qs,
    const float* __restrict__ ks, float* __restrict__ out_o,
    float* __restrict__ out_a, float* __restrict__ out_s)
{
    __shared__ __align__(16) _Float16 Kb[TK][KSTR];   // 8704 B (aliased by Obuf)
    __shared__ __align__(16) _Float16 Vt[D][KSTR];    // 8704 B
    __shared__ float rsumf[32];                       // total ~17.5 KB
    float* Obuf = (float*)&Kb[0][0];                  // [32][68] f32, post-loop

    const int t  = threadIdx.x;
    const int w  = t >> 6;
    const int l  = t & 63;
    const int lr = l & 15;
    const int lg = l >> 4;
    const int qt = w >> 2;     // q 16-row tile (0/1)
    const int kv = w & 3;      // k-slice 0..3 (16 k each within the chunk)

    // XCD pinning: wg%8 == XCD; 32 q-tiles of one batch share one XCD's L2.
    const int wg = blockIdx.x;
    const int b  = ((wg >> 8) << 3) | (wg & 7);
    const int q0 = ((wg >> 3) & 31) * 32;

    const size_t inb = (size_t)b * (N * D);
    const size_t sb  = (size_t)b * N * N + (size_t)q0 * N;

    // ---- Q fragment (B-operand of swapped QK: col=lr -> q-row, elems = d) ----
    half8 qa[2];
    {
        const float* qp  = q  + inb + (size_t)(q0 + qt * 16 + lr) * D + lg * 8;
        const float* qsp = qs + inb + (size_t)(q0 + qt * 16 + lr) * D + lg * 8;
#pragma unroll
        for (int kst = 0; kst < 2; ++kst) {
            f32x4 a0 = *(const f32x4*)(qp + kst * 32);
            f32x4 a1 = *(const f32x4*)(qp + kst * 32 + 4);
            f32x4 c0 = *(const f32x4*)(qsp + kst * 32);
            f32x4 c1 = *(const f32x4*)(qsp + kst * 32 + 4);
            f32x4 s0 = a0 + c0, s1 = a1 + c1;
            union { half8 h8; fp16x2 h2[4]; } u;
            u.h2[0] = __builtin_amdgcn_cvt_pkrtz(s0[0], s0[1]);
            u.h2[1] = __builtin_amdgcn_cvt_pkrtz(s0[2], s0[3]);
            u.h2[2] = __builtin_amdgcn_cvt_pkrtz(s1[0], s1[1]);
            u.h2[3] = __builtin_amdgcn_cvt_pkrtz(s1[2], s1[3]);
            qa[kst] = u.h8;
        }
    }

    // ---- staging (r16-verbatim): waves 0-3 stage K+KS, waves 4-7 stage V ----
    const int  ts = t & 255;
    const bool kstager = (w < 4);

    auto STAGE = [&](int kc) {
        if (kstager) {          // fused Kf = K + KS, row-major
            const f32x4* kbp = (const f32x4*)(k  + inb + (size_t)kc * TK * D);
            const f32x4* sbp = (const f32x4*)(ks + inb + (size_t)kc * TK * D);
#pragma unroll
            for (int h = 0; h < 2; ++h) {
                f32x4 k0 = kbp[(2 * h)     * 256 + ts];
                f32x4 k1 = kbp[(2 * h + 1) * 256 + ts];
                f32x4 s0 = sbp[(2 * h)     * 256 + ts];
                f32x4 s1 = sbp[(2 * h + 1) * 256 + ts];
                f32x4 m0 = k0 + s0, m1 = k1 + s1;
                const int row0 = (2 * h) * 16 + (ts >> 4);
                const int col  = (ts & 15) * 4;
                union { half4 h4; fp16x2 h2[2]; } u0, u1;
                u0.h2[0] = __builtin_amdgcn_cvt_pkrtz(m0[0], m0[1]);
                u0.h2[1] = __builtin_amdgcn_cvt_pkrtz(m0[2], m0[3]);
                u1.h2[0] = __builtin_amdgcn_cvt_pkrtz(m1[0], m1[1]);
                u1.h2[1] = __builtin_amdgcn_cvt_pkrtz(m1[2], m1[3]);
                *(half4*)&Kb[row0][col]      = u0.h4;
                *(half4*)&Kb[row0 + 16][col] = u1.h4;
            }
        } else {                // V 4x4 register transpose -> Vt[d][kk]
            const f32x4* vbp = (const f32x4*)(v + inb + (size_t)kc * TK * D);
            f32x4 vr0 = vbp[((ts >> 4) * 4 + 0) * 16 + (ts & 15)];
            f32x4 vr1 = vbp[((ts >> 4) * 4 + 1) * 16 + (ts & 15)];
            f32x4 vr2 = vbp[((ts >> 4) * 4 + 2) * 16 + (ts & 15)];
            f32x4 vr3 = vbp[((ts >> 4) * 4 + 3) * 16 + (ts & 15)];
            const int br4 = (ts >> 4) * 4, bc4 = (ts & 15) * 4;
#pragma unroll
            for (int c = 0; c < 4; ++c) {
                union { half4 h4; fp16x2 h2[2]; } u;
                u.h2[0] = __builtin_amdgcn_cvt_pkrtz(vr0[c], vr1[c]);
                u.h2[1] = __builtin_amdgcn_cvt_pkrtz(vr2[c], vr3[c]);
                *(half4*)&Vt[bc4 + c][br4] = u.h4;
            }
        }
    };

    f32x4 oacc[4];   // O partials over this wave's k-slice, [d-tile]
#pragma unroll
    for (int dt = 0; dt < 4; ++dt) oacc[dt] = (f32x4){0.f, 0.f, 0.f, 0.f};
    float rs = 0.0f;

    for (int kc = 0; kc < NC; ++kc) {
        __syncthreads();   // bar0: prior chunk's Kb/Vt reads complete
        STAGE(kc);
        __syncthreads();   // bar1: staging visible

        // --- swapped QK^T: A = Kb k-rows, B = qa -> S^T tile.
        //     lane: q = qt*16+lr, k = kc*64 + kv*16 + 4*lg + r ---
        half8 ka0 = *(const half8*)&Kb[kv * 16 + lr][lg * 8];
        half8 ka1 = *(const half8*)&Kb[kv * 16 + lr][32 + lg * 8];
        f32x4 ac = {0.f, 0.f, 0.f, 0.f};
        ac = __builtin_amdgcn_mfma_f32_16x16x32_f16(ka0, qa[0], ac, 0, 0, 0);
        ac = __builtin_amdgcn_mfma_f32_16x16x32_f16(ka1, qa[1], ac, 0, 0, 0);
        f32x4 sv = { ac[0] * 0.125f, ac[1] * 0.125f,
                     ac[2] * 0.125f, ac[3] * 0.125f };

        // out_s: register-direct, 16B/lane, 64B sector pieces (r4-verified clean)
        *(f32x4*)(out_s + sb + (size_t)(qt * 16 + lr) * N
                  + kc * TK + kv * 16 + lg * 4) = sv;

        // P = exp(S-12): computed exactly ONCE per element
        float e0 = __builtin_amdgcn_exp2f(__builtin_fmaf(sv[0], LOG2E, ESHIFT));
        float e1 = __builtin_amdgcn_exp2f(__builtin_fmaf(sv[1], LOG2E, ESHIFT));
        float e2 = __builtin_amdgcn_exp2f(__builtin_fmaf(sv[2], LOG2E, ESHIFT));
        float e3 = __builtin_amdgcn_exp2f(__builtin_fmaf(sv[3], LOG2E, ESHIFT));
        rs += (e0 + e1) + (e2 + e3);
        union { half4 h4; fp16x2 h2[2]; } up;
        up.h2[0] = __builtin_amdgcn_cvt_pkrtz(e0, e1);
        up.h2[1] = __builtin_amdgcn_cvt_pkrtz(e2, e3);
        const half4 pa = up.h4;   // == PV A-frag (row=lr=q, k=4*lg+i)

        // --- PV: O[q][d] += P[q][k-slice] V[k-slice][d], 16x16x16 ---
#pragma unroll
        for (int dt = 0; dt < 4; ++dt) {
            half4 vb = *(const half4*)&Vt[dt * 16 + lr][kv * 16 + lg * 4];
            oacc[dt] = __builtin_amdgcn_mfma_f32_16x16x16f16(pa, vb, oacc[dt], 0, 0, 0);
        }
    }

    __syncthreads();   // all Kb/Vt reads done; Kb region becomes Obuf
    for (int i = t; i < 32 * 68; i += 512) Obuf[i] = 0.0f;
    if (t < 32) rsumf[t] = 0.0f;
    __syncthreads();

    // ---- rowsum: lane rs is the (kv, lg) partial of q = qt*16+lr ----
    rs += __shfl_xor(rs, 16);
    rs += __shfl_xor(rs, 32);
    if (l < 16) atomicAdd(&rsumf[qt * 16 + l], rs);

    // ---- O partials: cross-wave k-slice reduction (D-frag: q=4*lg+r, d=lr) ----
#pragma unroll
    for (int dt = 0; dt < 4; ++dt)
#pragma unroll
    for (int r = 0; r < 4; ++r)
        atomicAdd(&Obuf[(qt * 16 + lg * 4 + r) * 68 + dt * 16 + lr], oacc[dt][r]);
    __syncthreads();
    if (t < 32) rsumf[t] = 1.0f / rsumf[t];
    __syncthreads();

    // ---- O store: 16 lanes x 16B contiguous per row ----
    {
        const int qo = t >> 4, doo = (t & 15) * 4;
        f32x4 ov = *(const f32x4*)&Obuf[qo * 68 + doo];
        const float iv = rsumf[qo];
        f32x4 o2 = { ov[0] * iv, ov[1] * iv, ov[2] * iv, ov[3] * iv };
        __builtin_nontemporal_store(o2,
            (f32x4*)(out_o + inb + (size_t)(q0 + qo) * D + doo));
    }

    // ---- out_a epilogue: replay own out_s slice (L2/L3-hot), exp*inv, NT ----
    {
        const int   arow = t >> 4;
        const int   ac0  = (t & 15) * 4;
        const float iva  = rsumf[arow];
        const float* sp  = out_s + sb + (size_t)arow * N + ac0;
        float*       ap  = out_a + sb + (size_t)arow * N + ac0;
#pragma unroll 4
        for (int cb = 0; cb < NC; ++cb) {
            f32x4 sv = *(const f32x4*)(sp + cb * TK);
            f32x4 av;
#pragma unroll
            for (int i = 0; i < 4; ++i)
                av[i] = __builtin_amdgcn_exp2f(__builtin_fmaf(sv[i], LOG2E, ESHIFT)) * iva;
            __builtin_nontemporal_store(av, (f32x4*)(ap + cb * TK));
        }
    }
}

extern "C" void kernel_launch(void* const* d_in, const int* in_sizes, int n_in,
                              void* d_out, int out_size, void* d_ws, size_t ws_size,
                              hipStream_t stream) {
    const float* q  = (const float*)d_in[0];
    const float* k  = (const float*)d_in[1];
    const float* v  = (const float*)d_in[2];
    const float* qs = (const float*)d_in[3];
    const float* ks = (const float*)d_in[4];

    float* out_o = (float*)d_out;                       // [64,1024,64]
    float* out_a = out_o + (size_t)BH * N * D;          // [64,1024,1024]
    float* out_s = out_a + (size_t)BH * N * N;          // [64,1024,1024]

    attn_fused_kernel<<<dim3(BH * (N / 32)), dim3(512), 0, stream>>>(
        q, k, v, qs, ks, out_o, out_a, out_s);
}

// Round 19
// 690.283 us; speedup vs baseline: 1.1705x; 1.1705x over previous
//
#include <hip/hip_runtime.h>
#include <math.h>

// Fused semantic attention — r16 structure at TM=64 (fixed-cost amortization).
// r18 lesson: register-direct out_s = 16 tx/instr vs Sst-staged 4 tx/instr ->
// keep r16's staging verbatim. r16's residual ~270 us = per-chunk FIXED cost
// (48 KB staging + 3 barriers + L2 latency) x 16 chunks x 8 generations.
// TM=64: same fixed cost amortized over 2x output (Kb/Vt fragments reused by
// 2 MFMAs each), generations 8 -> 4; at VGPR<=64 + LDS 35.1 KB the whole
// 1024-block grid is co-resident (256 CU x 4). Unchanged: 3 plain barriers
// per chunk, pkrtz, exp2-fma, cacheable out_s + L2-replay out_a epilogue,
// XCD pinning.

#define BH 64
#define N 1024
#define D 64
#define TM 64         // q rows per block
#define TK 64
#define NC (N / TK)   // 16
#define KSTR 68
#define SSTR 68
#define LOG2E 1.44269504088896f
#define ESHIFT (-17.3123404907f)   // -12 * log2(e)

typedef float    f32x4 __attribute__((ext_vector_type(4)));
typedef _Float16 half8 __attribute__((ext_vector_type(8)));
typedef _Float16 half4 __attribute__((ext_vector_type(4)));
typedef __fp16   fp16x2 __attribute__((ext_vector_type(2)));  // cvt_pkrtz result

__global__ __launch_bounds__(512, 4) void attn_fused_kernel(
    const float* __restrict__ q, const float* __restrict__ k,
    const float* __restrict__ v, const float* __restrict__ qsem,
    const float* __restrict__ ks, float* __restrict__ out_o,
    float* __restrict__ out_a, float* __restrict__ out_s)
{
    __shared__ __align__(16) _Float16 Kb[TK][KSTR];   //  8704 B
    __shared__ __align__(16) _Float16 Vt[D][KSTR];    //  8704 B
    __shared__ __align__(16) float    Sst[TM][SSTR];  // 17408 B
    __shared__ float rsumf[TM];                       // total ~35.1 KB

    const int t  = threadIdx.x;
    const int w  = t >> 6;
    const int l  = t & 63;
    const int lr = l & 15;
    const int lg = l >> 4;
    const int qt = w >> 2;     // wave's q 32-row half (2 x 16-row subtiles)
    const int kt = w & 3;      // QK: k 16-col tile; PV: d 16-col tile

    // XCD pinning: wg%8 == XCD; 16 q-tiles of one batch share one XCD's L2.
    const int wg = blockIdx.x;                 // 1024 blocks
    const int b  = ((wg >> 7) << 3) | (wg & 7);
    const int q0 = ((wg >> 3) & 15) * TM;

    const size_t inb = (size_t)b * (N * D);
    const size_t sb  = (size_t)b * N * N + (size_t)q0 * N;

    // ---- Q fragments: 2 q-subtiles (rows q0+(qt*2+qs)*16+lr), pkrtz packs ----
    half8 qa[2][2];   // [qs][kst]
#pragma unroll
    for (int qs = 0; qs < 2; ++qs) {
        const float* qp  = q    + inb + (size_t)(q0 + (qt * 2 + qs) * 16 + lr) * D + lg * 8;
        const float* qsp = qsem + inb + (size_t)(q0 + (qt * 2 + qs) * 16 + lr) * D + lg * 8;
#pragma unroll
        for (int kst = 0; kst < 2; ++kst) {
            f32x4 a0 = *(const f32x4*)(qp + kst * 32);
            f32x4 a1 = *(const f32x4*)(qp + kst * 32 + 4);
            f32x4 c0 = *(const f32x4*)(qsp + kst * 32);
            f32x4 c1 = *(const f32x4*)(qsp + kst * 32 + 4);
            f32x4 s0 = a0 + c0, s1 = a1 + c1;
            union { half8 h8; fp16x2 h2[4]; } u;
            u.h2[0] = __builtin_amdgcn_cvt_pkrtz(s0[0], s0[1]);
            u.h2[1] = __builtin_amdgcn_cvt_pkrtz(s0[2], s0[3]);
            u.h2[2] = __builtin_amdgcn_cvt_pkrtz(s1[0], s1[1]);
            u.h2[3] = __builtin_amdgcn_cvt_pkrtz(s1[2], s1[3]);
            qa[qs][kst] = u.h8;
        }
    }

    // ---- staging (r16-verbatim): waves 0-3 stage K+KS, waves 4-7 stage V ----
    const int  ts = t & 255;
    const bool kstager = (w < 4);

    auto STAGE = [&](int kc) {
        if (kstager) {
            const f32x4* kbp = (const f32x4*)(k  + inb + (size_t)kc * TK * D);
            const f32x4* sbp = (const f32x4*)(ks + inb + (size_t)kc * TK * D);
#pragma unroll
            for (int h = 0; h < 2; ++h) {
                f32x4 k0 = kbp[(2 * h)     * 256 + ts];
                f32x4 k1 = kbp[(2 * h + 1) * 256 + ts];
                f32x4 s0 = sbp[(2 * h)     * 256 + ts];
                f32x4 s1 = sbp[(2 * h + 1) * 256 + ts];
                f32x4 m0 = k0 + s0, m1 = k1 + s1;
                const int row0 = (2 * h) * 16 + (ts >> 4);
                const int col  = (ts & 15) * 4;
                union { half4 h4; fp16x2 h2[2]; } u0, u1;
                u0.h2[0] = __builtin_amdgcn_cvt_pkrtz(m0[0], m0[1]);
                u0.h2[1] = __builtin_amdgcn_cvt_pkrtz(m0[2], m0[3]);
                u1.h2[0] = __builtin_amdgcn_cvt_pkrtz(m1[0], m1[1]);
                u1.h2[1] = __builtin_amdgcn_cvt_pkrtz(m1[2], m1[3]);
                *(half4*)&Kb[row0][col]      = u0.h4;
                *(half4*)&Kb[row0 + 16][col] = u1.h4;
            }
        } else {
            const f32x4* vbp = (const f32x4*)(v + inb + (size_t)kc * TK * D);
            f32x4 vr0 = vbp[((ts >> 4) * 4 + 0) * 16 + (ts & 15)];
            f32x4 vr1 = vbp[((ts >> 4) * 4 + 1) * 16 + (ts & 15)];
            f32x4 vr2 = vbp[((ts >> 4) * 4 + 2) * 16 + (ts & 15)];
            f32x4 vr3 = vbp[((ts >> 4) * 4 + 3) * 16 + (ts & 15)];
            const int br4 = (ts >> 4) * 4, bc4 = (ts & 15) * 4;
#pragma unroll
            for (int c = 0; c < 4; ++c) {
                union { half4 h4; fp16x2 h2[2]; } u;
                u.h2[0] = __builtin_amdgcn_cvt_pkrtz(vr0[c], vr1[c]);
                u.h2[1] = __builtin_amdgcn_cvt_pkrtz(vr2[c], vr3[c]);
                *(half4*)&Vt[bc4 + c][br4] = u.h4;
            }
        }
    };

    f32x4 oacc[2];
    oacc[0] = (f32x4){0.f, 0.f, 0.f, 0.f};
    oacc[1] = (f32x4){0.f, 0.f, 0.f, 0.f};
    float rs[2] = {0.f, 0.f};

    for (int kc = 0; kc < NC; ++kc) {
        __syncthreads();   // bar0: prior chunk's Kb/Vt/Sst reads complete
        STAGE(kc);
        __syncthreads();   // bar1: staging visible

        // --- QK^T: Kb fragment read ONCE, used by both q-subtiles ---
        {
            half8 kb0 = *(const half8*)&Kb[kt * 16 + lr][lg * 8];
            half8 kb1 = *(const half8*)&Kb[kt * 16 + lr][32 + lg * 8];
#pragma unroll
            for (int qs = 0; qs < 2; ++qs) {
                f32x4 ac = {0.f, 0.f, 0.f, 0.f};
                ac = __builtin_amdgcn_mfma_f32_16x16x32_f16(qa[qs][0], kb0, ac, 0, 0, 0);
                ac = __builtin_amdgcn_mfma_f32_16x16x32_f16(qa[qs][1], kb1, ac, 0, 0, 0);
#pragma unroll
                for (int r = 0; r < 4; ++r)   // C/D: col=lr, row=4*lg+r
                    Sst[(qt * 2 + qs) * 16 + lg * 4 + r][kt * 16 + lr] = ac[r] * 0.125f;
            }
        }
        __syncthreads();   // bar2: Sst visible

        // --- out_s: cacheable coalesced, 64 rows in 2 groups ---
#pragma unroll
        for (int h = 0; h < 2; ++h) {
            const int srow = h * 32 + (t >> 4);
            f32x4 sv = *(const f32x4*)&Sst[srow][(t & 15) * 4];
            *(f32x4*)(out_s + sb + (size_t)srow * N + kc * TK + (t & 15) * 4) = sv;
        }

        // --- P = exp(S-12); PV MFMA (Vt fragment read once per kst, used 2x) ---
#pragma unroll
        for (int kst = 0; kst < 2; ++kst) {
            half8 vb = *(const half8*)&Vt[kt * 16 + lr][kst * 32 + lg * 8];
#pragma unroll
            for (int qs = 0; qs < 2; ++qs) {
                const int prow = (qt * 2 + qs) * 16 + lr;
                f32x4 s0 = *(const f32x4*)&Sst[prow][kst * 32 + lg * 8];
                f32x4 s1 = *(const f32x4*)&Sst[prow][kst * 32 + lg * 8 + 4];
                float e0 = __builtin_amdgcn_exp2f(__builtin_fmaf(s0[0], LOG2E, ESHIFT));
                float e1 = __builtin_amdgcn_exp2f(__builtin_fmaf(s0[1], LOG2E, ESHIFT));
                float e2 = __builtin_amdgcn_exp2f(__builtin_fmaf(s0[2], LOG2E, ESHIFT));
                float e3 = __builtin_amdgcn_exp2f(__builtin_fmaf(s0[3], LOG2E, ESHIFT));
                float e4 = __builtin_amdgcn_exp2f(__builtin_fmaf(s1[0], LOG2E, ESHIFT));
                float e5 = __builtin_amdgcn_exp2f(__builtin_fmaf(s1[1], LOG2E, ESHIFT));
                float e6 = __builtin_amdgcn_exp2f(__builtin_fmaf(s1[2], LOG2E, ESHIFT));
                float e7 = __builtin_amdgcn_exp2f(__builtin_fmaf(s1[3], LOG2E, ESHIFT));
                if (kt == 0)
                    rs[qs] += ((e0 + e1) + (e2 + e3)) + ((e4 + e5) + (e6 + e7));
                union { half8 h8; fp16x2 h2[4]; } u;
                u.h2[0] = __builtin_amdgcn_cvt_pkrtz(e0, e1);
                u.h2[1] = __builtin_amdgcn_cvt_pkrtz(e2, e3);
                u.h2[2] = __builtin_amdgcn_cvt_pkrtz(e4, e5);
                u.h2[3] = __builtin_amdgcn_cvt_pkrtz(e6, e7);
                oacc[qs] = __builtin_amdgcn_mfma_f32_16x16x32_f16(u.h8, vb, oacc[qs], 0, 0, 0);
            }
        }
    }

    // ---- rowsum finalize (kt==0 waves hold lg-group partials) ----
    if (kt == 0) {
#pragma unroll
        for (int qs = 0; qs < 2; ++qs) {
            float x = rs[qs];
            x += __shfl_xor(x, 16);
            x += __shfl_xor(x, 32);
            if (l < 16) rsumf[(qt * 2 + qs) * 16 + l] = x;
        }
    }
    __syncthreads();
    if (t < TM) rsumf[t] = 1.0f / rsumf[t];
    __syncthreads();

    // ---- O: scale into Sst, coalesced NT store (64 rows) ----
#pragma unroll
    for (int qs = 0; qs < 2; ++qs)
#pragma unroll
    for (int r = 0; r < 4; ++r) {
        const int row = (qt * 2 + qs) * 16 + lg * 4 + r;
        Sst[row][kt * 16 + lr] = oacc[qs][r] * rsumf[row];
    }
    __syncthreads();
#pragma unroll
    for (int h = 0; h < 2; ++h) {
        const int srow = h * 32 + (t >> 4);
        f32x4 ov = *(const f32x4*)&Sst[srow][(t & 15) * 4];
        __builtin_nontemporal_store(ov,
            (f32x4*)(out_o + inb + (size_t)(q0 + srow) * D + (t & 15) * 4));
    }

    // ---- out_a epilogue: replay own out_s slice (L2/L3-hot), exp*inv, NT ----
#pragma unroll
    for (int h = 0; h < 2; ++h) {
        const int   arow = h * 32 + (t >> 4);
        const int   ac0  = (t & 15) * 4;
        const float iva  = rsumf[arow];
        const float* sp  = out_s + sb + (size_t)arow * N + ac0;
        float*       ap  = out_a + sb + (size_t)arow * N + ac0;
#pragma unroll 4
        for (int cb = 0; cb < NC; ++cb) {
            f32x4 sv = *(const f32x4*)(sp + cb * TK);
            f32x4 av;
#pragma unroll
            for (int i = 0; i < 4; ++i)
                av[i] = __builtin_amdgcn_exp2f(__builtin_fmaf(sv[i], LOG2E, ESHIFT)) * iva;
            __builtin_nontemporal_store(av, (f32x4*)(ap + cb * TK));
        }
    }
}

extern "C" void kernel_launch(void* const* d_in, const int* in_sizes, int n_in,
                              void* d_out, int out_size, void* d_ws, size_t ws_size,
                              hipStream_t stream) {
    const float* q  = (const float*)d_in[0];
    const float* k  = (const float*)d_in[1];
    const float* v  = (const float*)d_in[2];
    const float* qs = (const float*)d_in[3];
    const float* ks = (const float*)d_in[4];

    float* out_o = (float*)d_out;                       // [64,1024,64]
    float* out_a = out_o + (size_t)BH * N * D;          // [64,1024,1024]
    float* out_s = out_a + (size_t)BH * N * N;          // [64,1024,1024]

    attn_fused_kernel<<<dim3(BH * (N / TM)), dim3(512), 0, stream>>>(
        q, k, v, qs, ks, out_o, out_a, out_s);
}

// Round 20
// 669.820 us; speedup vs baseline: 1.2062x; 1.0306x over previous
//
#include <hip/hip_runtime.h>
#include <math.h>

// Fused semantic attention — r19 structure at TM=128 (second amortization
// doubling). r16->r19 (TM 32->64) paid +28 us by halving per-output fixed
// cost (48 KB staging + 3 barriers per chunk) and block generations. TM=128:
// grid 512 (fully co-resident even at 2 blocks/CU), K/V re-read per batch
// 16x->8x, Kb/Vt fragments each feed 4 MFMAs. LDS 52.7 KB -> 3 blocks/CU by
// LDS; VGPR est ~80-95 under the (512,4) cap. All else r19-verbatim: 3 plain
// barriers/chunk, Sst-staged 256B stores, pkrtz, exp2-fma, cacheable out_s +
// L2-replay out_a epilogue, XCD pinning.

#define BH 64
#define N 1024
#define D 64
#define TM 128        // q rows per block
#define TK 64
#define NC (N / TK)   // 16
#define KSTR 68
#define SSTR 68
#define LOG2E 1.44269504088896f
#define ESHIFT (-17.3123404907f)   // -12 * log2(e)

typedef float    f32x4 __attribute__((ext_vector_type(4)));
typedef _Float16 half8 __attribute__((ext_vector_type(8)));
typedef _Float16 half4 __attribute__((ext_vector_type(4)));
typedef __fp16   fp16x2 __attribute__((ext_vector_type(2)));  // cvt_pkrtz result

__global__ __launch_bounds__(512, 4) void attn_fused_kernel(
    const float* __restrict__ q, const float* __restrict__ k,
    const float* __restrict__ v, const float* __restrict__ qsem,
    const float* __restrict__ ks, float* __restrict__ out_o,
    float* __restrict__ out_a, float* __restrict__ out_s)
{
    __shared__ __align__(16) _Float16 Kb[TK][KSTR];   //  8704 B
    __shared__ __align__(16) _Float16 Vt[D][KSTR];    //  8704 B
    __shared__ __align__(16) float    Sst[TM][SSTR];  // 34816 B
    __shared__ float rsumf[TM];                       // total ~52.7 KB

    const int t  = threadIdx.x;
    const int w  = t >> 6;
    const int l  = t & 63;
    const int lr = l & 15;
    const int lg = l >> 4;
    const int qt = w >> 2;     // wave's 64-row half (4 x 16-row subtiles)
    const int kt = w & 3;      // QK: k 16-col tile; PV: d 16-col tile

    // XCD pinning: wg%8 == XCD; 8 q-tiles of one batch share one XCD's L2.
    const int wg = blockIdx.x;                 // 512 blocks
    const int b  = ((wg >> 6) << 3) | (wg & 7);
    const int q0 = ((wg >> 3) & 7) * TM;

    const size_t inb = (size_t)b * (N * D);
    const size_t sb  = (size_t)b * N * N + (size_t)q0 * N;

    // ---- Q fragments: 4 q-subtiles (rows q0+qt*64+qs*16+lr), pkrtz packs ----
    half8 qa[4][2];   // [qs][kst]
#pragma unroll
    for (int qs = 0; qs < 4; ++qs) {
        const float* qp  = q    + inb + (size_t)(q0 + qt * 64 + qs * 16 + lr) * D + lg * 8;
        const float* qsp = qsem + inb + (size_t)(q0 + qt * 64 + qs * 16 + lr) * D + lg * 8;
#pragma unroll
        for (int kst = 0; kst < 2; ++kst) {
            f32x4 a0 = *(const f32x4*)(qp + kst * 32);
            f32x4 a1 = *(const f32x4*)(qp + kst * 32 + 4);
            f32x4 c0 = *(const f32x4*)(qsp + kst * 32);
            f32x4 c1 = *(const f32x4*)(qsp + kst * 32 + 4);
            f32x4 s0 = a0 + c0, s1 = a1 + c1;
            union { half8 h8; fp16x2 h2[4]; } u;
            u.h2[0] = __builtin_amdgcn_cvt_pkrtz(s0[0], s0[1]);
            u.h2[1] = __builtin_amdgcn_cvt_pkrtz(s0[2], s0[3]);
            u.h2[2] = __builtin_amdgcn_cvt_pkrtz(s1[0], s1[1]);
            u.h2[3] = __builtin_amdgcn_cvt_pkrtz(s1[2], s1[3]);
            qa[qs][kst] = u.h8;
        }
    }

    // ---- staging (r16-verbatim): waves 0-3 stage K+KS, waves 4-7 stage V ----
    const int  ts = t & 255;
    const bool kstager = (w < 4);

    auto STAGE = [&](int kc) {
        if (kstager) {
            const f32x4* kbp = (const f32x4*)(k  + inb + (size_t)kc * TK * D);
            const f32x4* sbp = (const f32x4*)(ks + inb + (size_t)kc * TK * D);
#pragma unroll
            for (int h = 0; h < 2; ++h) {
                f32x4 k0 = kbp[(2 * h)     * 256 + ts];
                f32x4 k1 = kbp[(2 * h + 1) * 256 + ts];
                f32x4 s0 = sbp[(2 * h)     * 256 + ts];
                f32x4 s1 = sbp[(2 * h + 1) * 256 + ts];
                f32x4 m0 = k0 + s0, m1 = k1 + s1;
                const int row0 = (2 * h) * 16 + (ts >> 4);
                const int col  = (ts & 15) * 4;
                union { half4 h4; fp16x2 h2[2]; } u0, u1;
                u0.h2[0] = __builtin_amdgcn_cvt_pkrtz(m0[0], m0[1]);
                u0.h2[1] = __builtin_amdgcn_cvt_pkrtz(m0[2], m0[3]);
                u1.h2[0] = __builtin_amdgcn_cvt_pkrtz(m1[0], m1[1]);
                u1.h2[1] = __builtin_amdgcn_cvt_pkrtz(m1[2], m1[3]);
                *(half4*)&Kb[row0][col]      = u0.h4;
                *(half4*)&Kb[row0 + 16][col] = u1.h4;
            }
        } else {
            const f32x4* vbp = (const f32x4*)(v + inb + (size_t)kc * TK * D);
            f32x4 vr0 = vbp[((ts >> 4) * 4 + 0) * 16 + (ts & 15)];
            f32x4 vr1 = vbp[((ts >> 4) * 4 + 1) * 16 + (ts & 15)];
            f32x4 vr2 = vbp[((ts >> 4) * 4 + 2) * 16 + (ts & 15)];
            f32x4 vr3 = vbp[((ts >> 4) * 4 + 3) * 16 + (ts & 15)];
            const int br4 = (ts >> 4) * 4, bc4 = (ts & 15) * 4;
#pragma unroll
            for (int c = 0; c < 4; ++c) {
                union { half4 h4; fp16x2 h2[2]; } u;
                u.h2[0] = __builtin_amdgcn_cvt_pkrtz(vr0[c], vr1[c]);
                u.h2[1] = __builtin_amdgcn_cvt_pkrtz(vr2[c], vr3[c]);
                *(half4*)&Vt[bc4 + c][br4] = u.h4;
            }
        }
    };

    f32x4 oacc[4];   // [qs]
#pragma unroll
    for (int qs = 0; qs < 4; ++qs) oacc[qs] = (f32x4){0.f, 0.f, 0.f, 0.f};
    float rs[4] = {0.f, 0.f, 0.f, 0.f};

    for (int kc = 0; kc < NC; ++kc) {
        __syncthreads();   // bar0: prior chunk's Kb/Vt/Sst reads complete
        STAGE(kc);
        __syncthreads();   // bar1: staging visible

        // --- QK^T: Kb fragment read ONCE, used by all 4 q-subtiles ---
        {
            half8 kb0 = *(const half8*)&Kb[kt * 16 + lr][lg * 8];
            half8 kb1 = *(const half8*)&Kb[kt * 16 + lr][32 + lg * 8];
#pragma unroll
            for (int qs = 0; qs < 4; ++qs) {
                f32x4 ac = {0.f, 0.f, 0.f, 0.f};
                ac = __builtin_amdgcn_mfma_f32_16x16x32_f16(qa[qs][0], kb0, ac, 0, 0, 0);
                ac = __builtin_amdgcn_mfma_f32_16x16x32_f16(qa[qs][1], kb1, ac, 0, 0, 0);
#pragma unroll
                for (int r = 0; r < 4; ++r)   // C/D: col=lr, row=4*lg+r
                    Sst[qt * 64 + qs * 16 + lg * 4 + r][kt * 16 + lr] = ac[r] * 0.125f;
            }
        }
        __syncthreads();   // bar2: Sst visible

        // --- out_s: cacheable coalesced, 128 rows in 4 groups ---
#pragma unroll
        for (int h = 0; h < 4; ++h) {
            const int srow = h * 32 + (t >> 4);
            f32x4 sv = *(const f32x4*)&Sst[srow][(t & 15) * 4];
            *(f32x4*)(out_s + sb + (size_t)srow * N + kc * TK + (t & 15) * 4) = sv;
        }

        // --- P = exp(S-12); PV MFMA (Vt fragment read once per kst, used 4x) ---
#pragma unroll
        for (int kst = 0; kst < 2; ++kst) {
            half8 vb = *(const half8*)&Vt[kt * 16 + lr][kst * 32 + lg * 8];
#pragma unroll
            for (int qs = 0; qs < 4; ++qs) {
                const int prow = qt * 64 + qs * 16 + lr;
                f32x4 s0 = *(const f32x4*)&Sst[prow][kst * 32 + lg * 8];
                f32x4 s1 = *(const f32x4*)&Sst[prow][kst * 32 + lg * 8 + 4];
                float e0 = __builtin_amdgcn_exp2f(__builtin_fmaf(s0[0], LOG2E, ESHIFT));
                float e1 = __builtin_amdgcn_exp2f(__builtin_fmaf(s0[1], LOG2E, ESHIFT));
                float e2 = __builtin_amdgcn_exp2f(__builtin_fmaf(s0[2], LOG2E, ESHIFT));
                float e3 = __builtin_amdgcn_exp2f(__builtin_fmaf(s0[3], LOG2E, ESHIFT));
                float e4 = __builtin_amdgcn_exp2f(__builtin_fmaf(s1[0], LOG2E, ESHIFT));
                float e5 = __builtin_amdgcn_exp2f(__builtin_fmaf(s1[1], LOG2E, ESHIFT));
                float e6 = __builtin_amdgcn_exp2f(__builtin_fmaf(s1[2], LOG2E, ESHIFT));
                float e7 = __builtin_amdgcn_exp2f(__builtin_fmaf(s1[3], LOG2E, ESHIFT));
                if (kt == 0)
                    rs[qs] += ((e0 + e1) + (e2 + e3)) + ((e4 + e5) + (e6 + e7));
                union { half8 h8; fp16x2 h2[4]; } u;
                u.h2[0] = __builtin_amdgcn_cvt_pkrtz(e0, e1);
                u.h2[1] = __builtin_amdgcn_cvt_pkrtz(e2, e3);
                u.h2[2] = __builtin_amdgcn_cvt_pkrtz(e4, e5);
                u.h2[3] = __builtin_amdgcn_cvt_pkrtz(e6, e7);
                oacc[qs] = __builtin_amdgcn_mfma_f32_16x16x32_f16(u.h8, vb, oacc[qs], 0, 0, 0);
            }
        }
    }

    // ---- rowsum finalize (kt==0 waves hold lg-group partials) ----
    if (kt == 0) {
#pragma unroll
        for (int qs = 0; qs < 4; ++qs) {
            float x = rs[qs];
            x += __shfl_xor(x, 16);
            x += __shfl_xor(x, 32);
            if (l < 16) rsumf[qt * 64 + qs * 16 + l] = x;
        }
    }
    __syncthreads();
    if (t < TM) rsumf[t] = 1.0f / rsumf[t];
    __syncthreads();

    // ---- O: scale into Sst, coalesced NT store (128 rows) ----
#pragma unroll
    for (int qs = 0; qs < 4; ++qs)
#pragma unroll
    for (int r = 0; r < 4; ++r) {
        const int row = qt * 64 + qs * 16 + lg * 4 + r;
        Sst[row][kt * 16 + lr] = oacc[qs][r] * rsumf[row];
    }
    __syncthreads();
#pragma unroll
    for (int h = 0; h < 4; ++h) {
        const int srow = h * 32 + (t >> 4);
        f32x4 ov = *(const f32x4*)&Sst[srow][(t & 15) * 4];
        __builtin_nontemporal_store(ov,
            (f32x4*)(out_o + inb + (size_t)(q0 + srow) * D + (t & 15) * 4));
    }

    // ---- out_a epilogue: replay own out_s slice (L2/L3-hot), exp*inv, NT ----
#pragma unroll
    for (int h = 0; h < 4; ++h) {
        const int   arow = h * 32 + (t >> 4);
        const int   ac0  = (t & 15) * 4;
        const float iva  = rsumf[arow];
        const float* sp  = out_s + sb + (size_t)arow * N + ac0;
        float*       ap  = out_a + sb + (size_t)arow * N + ac0;
#pragma unroll 4
        for (int cb = 0; cb < NC; ++cb) {
            f32x4 sv = *(const f32x4*)(sp + cb * TK);
            f32x4 av;
#pragma unroll
            for (int i = 0; i < 4; ++i)
                av[i] = __builtin_amdgcn_exp2f(__builtin_fmaf(sv[i], LOG2E, ESHIFT)) * iva;
            __builtin_nontemporal_store(av, (f32x4*)(ap + cb * TK));
        }
    }
}

extern "C" void kernel_launch(void* const* d_in, const int* in_sizes, int n_in,
                              void* d_out, int out_size, void* d_ws, size_t ws_size,
                              hipStream_t stream) {
    const float* q  = (const float*)d_in[0];
    const float* k  = (const float*)d_in[1];
    const float* v  = (const float*)d_in[2];
    const float* qs = (const float*)d_in[3];
    const float* ks = (const float*)d_in[4];

    float* out_o = (float*)d_out;                       // [64,1024,64]
    float* out_a = out_o + (size_t)BH * N * D;          // [64,1024,1024]
    float* out_s = out_a + (size_t)BH * N * N;          // [64,1024,1024]

    attn_fused_kernel<<<dim3(BH * (N / TM)), dim3(512), 0, stream>>>(
        q, k, v, qs, ks, out_o, out_a, out_s);
}